// Round 7
// baseline (472.136 us; speedup 1.0000x reference)
//
#include <hip/hip_runtime.h>
#include <math.h>

#define NU 100000
#define NI 50000
#define NT 150000      // NU + NI
#define D  64
#define NNZ_ 4000000
#define BATCH_ 4096
#define WDECAY 1e-4f

#define BROWS 512                  // rows per bucket (power of 2: shift 9)
#define NBKT 293                   // ceil(NT / BROWS)
#define BCAP 15360                 // bucket capacity (mean 13653, sigma ~117 -> +14.6 sigma)
#define CURS 16                    // cursor stride (64B anti-contention pad)
#define EPB 16                     // edges per thread in binA
#define BATCH_E (256 * EPB)        // 4096 edges per block-batch
#define NBLK_A ((NNZ_ + BATCH_E - 1) / BATCH_E)   // 977
#define NBLO 512                   // loss blocks (partials, no atomics)

static __device__ __forceinline__ float bf2f(ushort u) {
    return __uint_as_float(((unsigned int)u) << 16);
}
static __device__ __forceinline__ float bflo(unsigned int u) {   // low bf16 of packed u32
    return __uint_as_float(u << 16);
}
static __device__ __forceinline__ float bfhi(unsigned int u) {   // high bf16
    return __uint_as_float(u & 0xffff0000u);
}
static __device__ __forceinline__ ushort f2bf(float f) {
    unsigned int u = __float_as_uint(f);
    u += 0x7FFF + ((u >> 16) & 1);      // RTNE
    return (ushort)(u >> 16);
}

// ---- init: cur0 = bf16(concat(ue, ie)) --------------------------------------
__global__ void init_kernel(const float* __restrict__ ue, const float* __restrict__ ie,
                            ushort* __restrict__ cur0) {
    int i = blockIdx.x * blockDim.x + threadIdx.x;
    const int total4 = NT * D / 4;
    if (i >= total4) return;
    const int usz4 = NU * D / 4;
    float4 v = (i < usz4) ? ((const float4*)ue)[i] : ((const float4*)ie)[i - usz4];
    ushort4 o;
    o.x = f2bf(v.x); o.y = f2bf(v.y); o.z = f2bf(v.z); o.w = f2bf(v.w);
    ((ushort4*)cur0)[i] = o;
}

// ---- binA: block-aggregated bucket append (runs are block-private) ----------
__global__ void binA_kernel(const int* __restrict__ rows, const int* __restrict__ cols,
                            const float* __restrict__ vals,
                            int* __restrict__ cursor, int2* __restrict__ binned) {
    __shared__ int cnt[NBKT];
    __shared__ int gbase[NBKT];
    int tid = threadIdx.x;
    int b0 = blockIdx.x * BATCH_E;
    for (int t = tid; t < NBKT; t += 256) cnt[t] = 0;
    __syncthreads();
    // phase 1: rank within (batch, bucket). pack = rl | (bkt<<9) | (rank<<18)
    int pack[EPB];
    #pragma unroll
    for (int k = 0; k < EPB; ++k) {
        int i = b0 + k * 256 + tid;
        if (i < NNZ_) {
            int r = __builtin_nontemporal_load(rows + i);
            int b = r >> 9;
            int rk = atomicAdd(&cnt[b], 1);
            pack[k] = (r & (BROWS - 1)) | (b << 9) | (rk << 18);
        } else pack[k] = -1;
    }
    __syncthreads();
    // phase 2: reserve one contiguous global run per bucket
    for (int t = tid; t < NBKT; t += 256) {
        int c = cnt[t];
        gbase[t] = c ? atomicAdd(&cursor[t * CURS], c) : 0;
    }
    __syncthreads();
    // phase 3: write
    #pragma unroll
    for (int k = 0; k < EPB; ++k) {
        int pk = pack[k];
        if (pk >= 0) {
            int i  = b0 + k * 256 + tid;
            int rl = pk & (BROWS - 1);
            int b  = (pk >> 9) & 511;
            int rk = pk >> 18;
            int2 e;
            e.x = rl | (__builtin_nontemporal_load(cols + i) << 9);
            e.y = __float_as_int(__builtin_nontemporal_load(vals + i));
            binned[(size_t)b * BCAP + gbase[b] + rk] = e;
        }
    }
}

// ---- bucket-base scan (293 buckets, single block) ---------------------------
__global__ void bscan_kernel(const int* __restrict__ cursor, int* __restrict__ bbase,
                             int* __restrict__ rowptr) {
    __shared__ int s[512];
    int t = threadIdx.x;
    int v = (t < NBKT) ? cursor[t * CURS] : 0;
    s[t] = v; __syncthreads();
    for (int off = 1; off < 512; off <<= 1) {
        int x = (t >= off) ? s[t - off] : 0;
        __syncthreads();
        s[t] += x;
        __syncthreads();
    }
    if (t < NBKT) bbase[t] = s[t] - v;
    if (t == 0) rowptr[NT] = NNZ_;
}

// ---- binB: per-bucket LDS counting sort (512 rows) -> CSR -------------------
__global__ void binB_kernel(const int2* __restrict__ binned, const int* __restrict__ cursor,
                            const int* __restrict__ bbase,
                            int2* __restrict__ colval, int* __restrict__ rowptr) {
    __shared__ int cnt[BROWS];
    __shared__ int sc[BROWS];
    __shared__ int offs[BROWS];
    int b   = blockIdx.x;
    int tid = threadIdx.x;
    int cb  = cursor[b * CURS];
    int base = bbase[b];
    const unsigned long long* eb8 = (const unsigned long long*)(binned + (size_t)b * BCAP);
    if (tid < BROWS) cnt[tid] = 0;
    __syncthreads();
    for (int i = tid; i < cb; i += 1024) {
        unsigned long long e = __builtin_nontemporal_load(eb8 + i);
        atomicAdd(&cnt[(int)e & (BROWS - 1)], 1);
    }
    __syncthreads();
    int v = 0;
    if (tid < BROWS) { v = cnt[tid]; sc[tid] = v; }
    __syncthreads();
    for (int off = 1; off < BROWS; off <<= 1) {
        int x = 0;
        if (tid < BROWS && tid >= off) x = sc[tid - off];
        __syncthreads();
        if (tid < BROWS) sc[tid] += x;
        __syncthreads();
    }
    if (tid < BROWS) {
        int excl = sc[tid] - v;
        offs[tid] = excl;
        int row = b * BROWS + tid;
        if (row < NT) rowptr[row] = base + excl;
    }
    __syncthreads();
    for (int i = tid; i < cb; i += 1024) {
        unsigned long long e = __builtin_nontemporal_load(eb8 + i);
        int ex = (int)e;
        int rl = ex & (BROWS - 1);
        int p  = base + atomicAdd(&offs[rl], 1);
        int2 cv; cv.x = ex >> 9; cv.y = (int)(e >> 32);
        colval[p] = cv;
    }
}

// ---- oct-ILP row core: 8 edges in flight, uint4 (16B) gathers ---------------
// lane = (g, gl): g = lane>>3 edge slot, gl = lane&7 -> dims gl*8..gl*8+7
// returns s0..s7 reduced across the 8 groups (all lanes hold final values)
static __device__ __forceinline__ void row_core(const int* __restrict__ rowptr,
                                                const int2* __restrict__ colval,
                                                const ushort* __restrict__ x,
                                                int r, int lane,
                                                float& s0, float& s1, float& s2, float& s3,
                                                float& s4, float& s5, float& s6, float& s7) {
    int g  = lane >> 3;
    int gl = lane & 7;
    int beg = rowptr[r], end = rowptr[r + 1];
    s0 = s1 = s2 = s3 = s4 = s5 = s6 = s7 = 0.f;
    const unsigned long long* cv8 = (const unsigned long long*)colval;
    for (int base = beg; base < end; base += 64) {
        int m = end - base; if (m > 64) m = 64;
        int idx = base + lane; if (idx > NNZ_ - 1) idx = NNZ_ - 1;
        unsigned long long e8 = __builtin_nontemporal_load(cv8 + idx);
        int cvx = (int)e8;
        int cvy = (int)(e8 >> 32);
        int ng = (m + 7) >> 3;
        #pragma unroll 8
        for (int j = 0; j < ng; ++j) {
            int e = 8 * j + g;
            int   c = __shfl(cvx, e);
            float v = __int_as_float(__shfl(cvy, e));
            if (e >= m) v = 0.f;
            uint4 w = *(const uint4*)(x + (size_t)c * D + gl * 8);
            s0 += v * bflo(w.x); s1 += v * bfhi(w.x);
            s2 += v * bflo(w.y); s3 += v * bfhi(w.y);
            s4 += v * bflo(w.z); s5 += v * bfhi(w.z);
            s6 += v * bflo(w.w); s7 += v * bfhi(w.w);
        }
    }
    #pragma unroll
    for (int off = 8; off < 64; off <<= 1) {
        s0 += __shfl_xor(s0, off); s1 += __shfl_xor(s1, off);
        s2 += __shfl_xor(s2, off); s3 += __shfl_xor(s3, off);
        s4 += __shfl_xor(s4, off); s5 += __shfl_xor(s5, off);
        s6 += __shfl_xor(s6, off); s7 += __shfl_xor(s7, off);
    }
}

// ---- SpMM (CSR gather): one wave per row ------------------------------------
__global__ void spmm_kernel(const int* __restrict__ rowptr, const int2* __restrict__ colval,
                            const ushort* __restrict__ x, ushort* __restrict__ y) {
    int gtid = blockIdx.x * blockDim.x + threadIdx.x;
    int r    = gtid >> 6;
    int lane = threadIdx.x & 63;
    if (r >= NT) return;
    float s0, s1, s2, s3, s4, s5, s6, s7;
    row_core(rowptr, colval, x, r, lane, s0, s1, s2, s3, s4, s5, s6, s7);
    if (lane < 8) {
        uint4 o;
        o.x = (unsigned)f2bf(s0) | ((unsigned)f2bf(s1) << 16);
        o.y = (unsigned)f2bf(s2) | ((unsigned)f2bf(s3) << 16);
        o.z = (unsigned)f2bf(s4) | ((unsigned)f2bf(s5) << 16);
        o.w = (unsigned)f2bf(s6) | ((unsigned)f2bf(s7) << 16);
        *(uint4*)(y + (size_t)r * D + lane * 8) = o;
    }
}

// ---- walk: layer-3 rows needed by the loss, one wave per (batch,role) -------
__global__ void walk_kernel(const ushort* __restrict__ o2,
                            const int* __restrict__ rowptr, const int2* __restrict__ colval,
                            const int* __restrict__ users, const int* __restrict__ pos,
                            const int* __restrict__ neg, float* __restrict__ wbuf) {
    int gtid = blockIdx.x * blockDim.x + threadIdx.x;
    int task = gtid >> 6;
    int lane = threadIdx.x & 63;
    if (task >= 3 * BATCH_) return;
    int role = task >> 12;                // BATCH_ = 4096
    int b    = task & (BATCH_ - 1);
    int r = (role == 0) ? users[b] : (role == 1) ? NU + pos[b] : NU + neg[b];
    float s0, s1, s2, s3, s4, s5, s6, s7;
    row_core(rowptr, colval, o2, r, lane, s0, s1, s2, s3, s4, s5, s6, s7);
    if (lane < 8) {
        float4 a; a.x = s0; a.y = s1; a.z = s2; a.w = s3;
        float4 c; c.x = s4; c.y = s5; c.z = s6; c.w = s7;
        float* dst = wbuf + (size_t)task * D + lane * 8;
        *(float4*)dst = a;
        *(float4*)(dst + 4) = c;
    }
}

// ---- loss: per-block partials (no global atomics) ---------------------------
__global__ void loss_kernel(const float* __restrict__ ue, const float* __restrict__ ie,
                            const ushort* __restrict__ o1, const ushort* __restrict__ o2,
                            const float* __restrict__ wbuf,
                            const int* __restrict__ users, const int* __restrict__ pos,
                            const int* __restrict__ neg, float* __restrict__ pbuf) {
    __shared__ float ssp[4];
    __shared__ float srg[4];
    int tid  = threadIdx.x;
    int wv   = tid >> 6;
    int lane = tid & 63;
    int wid  = blockIdx.x * 4 + wv;
    const int nw = NBLO * 4;
    float sp_acc = 0.f, rg_acc = 0.f;
    for (int b = wid; b < BATCH_; b += nw) {
        int u = users[b], p = pos[b], n = neg[b];
        int ru = u, rp = NU + p, rn = NU + n;
        float uo = ue[(size_t)u * D + lane];
        float po = ie[(size_t)p * D + lane];
        float no = ie[(size_t)n * D + lane];
        float lu = uo + bf2f(o1[(size_t)ru * D + lane]) + bf2f(o2[(size_t)ru * D + lane])
                      + wbuf[(size_t)(0 * BATCH_ + b) * D + lane];
        float lp = po + bf2f(o1[(size_t)rp * D + lane]) + bf2f(o2[(size_t)rp * D + lane])
                      + wbuf[(size_t)(1 * BATCH_ + b) * D + lane];
        float ln_ = no + bf2f(o1[(size_t)rn * D + lane]) + bf2f(o2[(size_t)rn * D + lane])
                      + wbuf[(size_t)(2 * BATCH_ + b) * D + lane];
        float ps = lu * lp;
        float ns = lu * ln_;
        float rg = uo * uo + po * po + no * no;
        #pragma unroll
        for (int off = 32; off > 0; off >>= 1) {
            ps += __shfl_down(ps, off);
            ns += __shfl_down(ns, off);
            rg += __shfl_down(rg, off);
        }
        if (lane == 0) {
            float diff = (ns - ps) * (1.0f / 16.0f);
            float sp = diff > 0.f ? diff + log1pf(expf(-diff)) : log1pf(expf(diff));
            sp_acc += sp;
            rg_acc += rg;
        }
    }
    if (lane == 0) { ssp[wv] = sp_acc; srg[wv] = rg_acc; }
    __syncthreads();
    if (tid == 0) {
        pbuf[blockIdx.x]        = ssp[0] + ssp[1] + ssp[2] + ssp[3];
        pbuf[NBLO + blockIdx.x] = srg[0] + srg[1] + srg[2] + srg[3];
    }
}

// ---- finalize: reduce 512 partials, emit loss -------------------------------
__global__ void finalize_kernel(const float* __restrict__ pbuf, float* __restrict__ out) {
    __shared__ float s1[NBLO];
    __shared__ float s2[NBLO];
    int t = threadIdx.x;
    s1[t] = pbuf[t];
    s2[t] = pbuf[NBLO + t];
    __syncthreads();
    for (int off = NBLO / 2; off > 0; off >>= 1) {
        if (t < off) { s1[t] += s1[t + off]; s2[t] += s2[t + off]; }
        __syncthreads();
    }
    if (t == 0)
        out[0] = s1[0] / (float)BATCH_ + WDECAY * 0.5f * s2[0] / (float)BATCH_;
}

extern "C" void kernel_launch(void* const* d_in, const int* in_sizes, int n_in,
                              void* d_out, int out_size, void* d_ws, size_t ws_size,
                              hipStream_t stream) {
    const float* user_emb = (const float*)d_in[0];
    const float* item_emb = (const float*)d_in[1];
    const int*   g_rows   = (const int*)d_in[2];
    const int*   g_cols   = (const int*)d_in[3];
    const float* g_vals   = (const float*)d_in[4];
    const int*   users    = (const int*)d_in[5];
    const int*   pos      = (const int*)d_in[6];
    const int*   neg      = (const int*)d_in[7];
    float* out = (float*)d_out;

    const size_t TABH = (size_t)NT * D * 2;            // 19.2 MB bf16 table
    char* ws = (char*)d_ws;
    ushort* cur0   = (ushort*)(ws);
    ushort* o1     = (ushort*)(ws + TABH);
    ushort* o2     = (ushort*)(ws + 2 * TABH);
    int2*   colval = (int2*)  (ws + 3 * TABH);                       // 32 MB
    char*   bpt    = ws + 3 * TABH + (size_t)NNZ_ * 8;
    int2*   binned = (int2*)  (bpt);                                 // 36.0 MB (dead after binB)
    float*  wbuf   = (float*)(bpt);                                  // aliases binned (walk)
    float*  pbuf   = (float*)(bpt + 4 * 1024 * 1024);                // aliases binned (loss)
    char*   p      = bpt + (size_t)NBKT * BCAP * 8;
    int*    rowptr = (int*)(p);      p += ((size_t)(NT + 1) * 4 + 255) / 256 * 256;
    int*    cursor = (int*)(p);      p += (size_t)NBKT * CURS * 4 + 256;
    int*    bbase  = (int*)(p);      p += 2048;

    hipMemsetAsync(cursor, 0, (size_t)NBKT * CURS * 4, stream);
    init_kernel<<<(NT * D / 4 + 255) / 256, 256, 0, stream>>>(user_emb, item_emb, cur0);

    binA_kernel<<<NBLK_A, 256, 0, stream>>>(g_rows, g_cols, g_vals, cursor, binned);
    bscan_kernel<<<1, 512, 0, stream>>>(cursor, bbase, rowptr);
    binB_kernel<<<NBKT, 1024, 0, stream>>>(binned, cursor, bbase, colval, rowptr);

    const int SPMM_BLOCKS = (NT + 3) / 4;   // one wave per row, 4 waves/block
    spmm_kernel<<<SPMM_BLOCKS, 256, 0, stream>>>(rowptr, colval, cur0, o1);
    spmm_kernel<<<SPMM_BLOCKS, 256, 0, stream>>>(rowptr, colval, o1, o2);

    walk_kernel<<<(3 * BATCH_ + 3) / 4, 256, 0, stream>>>(o2, rowptr, colval,
                                                          users, pos, neg, wbuf);
    loss_kernel<<<NBLO, 256, 0, stream>>>(user_emb, item_emb, o1, o2, wbuf,
                                          users, pos, neg, pbuf);
    finalize_kernel<<<1, NBLO, 0, stream>>>(pbuf, out);
}